// Round 1
// baseline (174.500 us; speedup 1.0000x reference)
//
#include <hip/hip_runtime.h>
#include <math.h>

// QuanvolutionHybrid: conv2x2/s2 -> weird reshape(196,4) -> L2 norm ->
// all-pairs cos^2 threshold 0.8 -> degree -> concat -> linear(10) -> log_softmax
// One block = one batch element. VALU-bound on the 196x196x4 pair loop.

#define NP 196      // num patches / rows
#define FEAT 980    // 784 + 196

__global__ __launch_bounds__(256) void quanv_kernel(
    const float* __restrict__ x,        // (8192, 784)
    const float* __restrict__ conv_w,   // (4,1,2,2) = 16
    const float* __restrict__ conv_b,   // (4,)
    const float* __restrict__ lin_w,    // (10, 980)
    const float* __restrict__ lin_b,    // (10,)
    float* __restrict__ out)            // (8192, 10)
{
    __shared__ float  s_x[784];
    __shared__ float4 s_nrm[NP];
    __shared__ float  s_feats[FEAT];
    __shared__ float  s_red[40];
    __shared__ float  s_logits[10];

    const int b = blockIdx.x;
    const int t = threadIdx.x;

    // ---- Phase 1: stage input image in LDS (coalesced float4) ----
    if (t < NP) {
        const float4* xin = (const float4*)(x + (size_t)b * 784);
        ((float4*)s_x)[t] = xin[t];
    }
    __syncthreads();

    // ---- Phase 2: 2x2/s2 conv -> flat[784] channel-major in LDS ----
    if (t < NP) {
        int h = t / 14, w = t - 14 * (t / 14);
        const float* r0 = s_x + (2 * h) * 28 + 2 * w;
        float x00 = r0[0], x01 = r0[1], x10 = r0[28], x11 = r0[29];
        #pragma unroll
        for (int c = 0; c < 4; ++c) {
            float f = conv_b[c]
                    + conv_w[c * 4 + 0] * x00 + conv_w[c * 4 + 1] * x01
                    + conv_w[c * 4 + 2] * x10 + conv_w[c * 4 + 3] * x11;
            s_feats[c * NP + t] = f;
        }
    }
    __syncthreads();

    // ---- Phase 3a: rows = 4 consecutive flat elems; L2-normalize ----
    if (t < NP) {
        float4 v = ((const float4*)s_feats)[t];   // flat[4t .. 4t+3]
        float n = sqrtf(v.x * v.x + v.y * v.y + v.z * v.z + v.w * v.w);
        float inv = 1.0f / (n + 1e-12f);
        float4 nv; nv.x = v.x * inv; nv.y = v.y * inv; nv.z = v.z * inv; nv.w = v.w * inv;
        s_nrm[t] = nv;
    }
    __syncthreads();

    // ---- Phase 3b: all-pairs cos^2 >= 0.8 -> degree (self included, -1) ----
    if (t < NP) {
        float4 my = s_nrm[t];
        float cnt = 0.0f;
        #pragma unroll 4
        for (int q = 0; q < NP; ++q) {
            float4 o = s_nrm[q];              // broadcast ds_read_b128
            float d = my.x * o.x + my.y * o.y + my.z * o.z + my.w * o.w;
            if (d * d >= 0.8f) cnt += 1.0f;
        }
        s_feats[784 + t] = cnt - 1.0f;        // remove self-edge
    }
    __syncthreads();

    // ---- Phase 4: logits[k] = feats . lin_w[k] + lin_b[k] ----
    float acc[10];
    #pragma unroll
    for (int k = 0; k < 10; ++k) acc[k] = 0.0f;
    for (int j = t; j < FEAT; j += 256) {
        float f = s_feats[j];
        #pragma unroll
        for (int k = 0; k < 10; ++k)
            acc[k] = fmaf(f, lin_w[k * FEAT + j], acc[k]);
    }
    // wave (64-lane) shuffle reduction
    #pragma unroll
    for (int off = 32; off > 0; off >>= 1) {
        #pragma unroll
        for (int k = 0; k < 10; ++k)
            acc[k] += __shfl_down(acc[k], off, 64);
    }
    int wave = t >> 6, lane = t & 63;
    if (lane == 0) {
        #pragma unroll
        for (int k = 0; k < 10; ++k) s_red[wave * 10 + k] = acc[k];
    }
    __syncthreads();
    if (t < 10) {
        float l = lin_b[t] + s_red[t] + s_red[10 + t] + s_red[20 + t] + s_red[30 + t];
        s_logits[t] = l;
    }
    __syncthreads();

    // ---- Phase 5: log_softmax over 10 logits ----
    if (t < 10) {
        float m = -INFINITY;
        #pragma unroll
        for (int j = 0; j < 10; ++j) m = fmaxf(m, s_logits[j]);
        float s = 0.0f;
        #pragma unroll
        for (int j = 0; j < 10; ++j) s += expf(s_logits[j] - m);
        out[(size_t)b * 10 + t] = s_logits[t] - m - logf(s);
    }
}

extern "C" void kernel_launch(void* const* d_in, const int* in_sizes, int n_in,
                              void* d_out, int out_size, void* d_ws, size_t ws_size,
                              hipStream_t stream) {
    const float* x      = (const float*)d_in[0];
    const float* conv_w = (const float*)d_in[1];
    const float* conv_b = (const float*)d_in[2];
    const float* lin_w  = (const float*)d_in[3];
    const float* lin_b  = (const float*)d_in[4];
    float* out = (float*)d_out;
    quanv_kernel<<<dim3(8192), dim3(256), 0, stream>>>(x, conv_w, conv_b, lin_w, lin_b, out);
}